// Round 11
// baseline (182.969 us; speedup 1.0000x reference)
//
#include <hip/hip_runtime.h>
#include <hip/hip_bf16.h>
#include <stdint.h>

#define DM   768
#define NH   12
#define DKH  64
#define BB   2
#define SS   2048
#define MT   (BB*SS)          // 4096 rows total
#define NQKV (3*DM)           // 2304

typedef __attribute__((ext_vector_type(8))) short short8;
typedef __attribute__((ext_vector_type(4))) float f32x4;

__device__ __forceinline__ unsigned short f2bf(float f) {
    union { float f; unsigned u; } v; v.f = f;
    unsigned r = v.u + 0x7fffu + ((v.u >> 16) & 1u);
    return (unsigned short)(r >> 16);
}

// async global->LDS, 16B per lane; dst = wave-uniform base + lane*16
__device__ __forceinline__ void gload_lds16(const unsigned short* g, unsigned short* l) {
    __builtin_amdgcn_global_load_lds((const __attribute__((address_space(1))) void*)g,
                                     (__attribute__((address_space(3))) void*)l, 16, 0, 0);
}

// ---- fused input/weight conversion (one launch) ----
__launch_bounds__(256)
__global__ void k_conv(const float* __restrict__ x, unsigned short* __restrict__ xb,
                       const float* __restrict__ wq, const float* __restrict__ wk,
                       const float* __restrict__ wv, const float* __restrict__ wo,
                       unsigned short* __restrict__ wT) {
    __shared__ float tile[32][33];
    const int t = threadIdx.x;
    if (blockIdx.x < 3072) {
        int i = blockIdx.x * 256 + t;
        const float4 v = ((const float4*)x)[i];
        ushort4 o;
        o.x = f2bf(v.x); o.y = f2bf(v.y); o.z = f2bf(v.z); o.w = f2bf(v.w);
        ((ushort4*)xb)[i] = o;
    } else {
        const int cid = blockIdx.x - 3072;            // 0..2303
        const int sel = cid / 576;
        const int rem = cid - sel * 576;
        const int kb = rem / 24, nb = rem - (rem / 24) * 24;
        const float* w = (sel == 0) ? wq : (sel == 1) ? wk : (sel == 2) ? wv : wo;
        const int k0 = kb * 32, n0 = nb * 32;
        const int tx = t & 31, ty = t >> 5;           // (32, 8)
        #pragma unroll
        for (int j = 0; j < 4; j++)
            tile[ty + 8*j][tx] = w[(size_t)(k0 + ty + 8*j) * DM + n0 + tx];
        __syncthreads();
        #pragma unroll
        for (int j = 0; j < 4; j++)
            wT[(size_t)(sel*DM + n0 + ty + 8*j) * DM + k0 + tx] = f2bf(tile[tx][ty + 8*j]);
    }
}

// ---- fused QKV projection, BK=32 (R9 form): Q,K [bh][s][dk] (Q pre-scaled), V^T [bh][dk][s]
__launch_bounds__(256)
__global__ void k_gemm_qkv(const unsigned short* __restrict__ xb,
                           const unsigned short* __restrict__ wT,
                           const float* __restrict__ bq, const float* __restrict__ bk,
                           const float* __restrict__ bv,
                           unsigned short* __restrict__ Qb,
                           unsigned short* __restrict__ Kb,
                           unsigned short* __restrict__ Vt) {
    __shared__ __align__(16) unsigned short As[128][32];
    __shared__ __align__(16) unsigned short Bs[128][32];
    const int t = threadIdx.x;
    const int m0 = blockIdx.x * 128;
    const int n0 = blockIdx.y * 128;
    const int wid = t >> 6, lane = t & 63, q4 = lane >> 4, l16 = lane & 15;
    const int wm = (wid >> 1) * 64, wn = (wid & 1) * 64;

    const int srow = wid * 32 + (lane >> 2);
    const int koff = (lane & 3) * 8;
    const unsigned short* AgL = xb + (size_t)(m0 + srow) * DM + koff;
    const unsigned short* AgH = AgL + (size_t)16 * DM;
    const unsigned short* BgL = wT + (size_t)(n0 + srow) * DM + koff;
    const unsigned short* BgH = BgL + (size_t)16 * DM;
    unsigned short* ldsA1 = &As[wid*32][0];
    unsigned short* ldsA2 = &As[wid*32 + 16][0];
    unsigned short* ldsB1 = &Bs[wid*32][0];
    unsigned short* ldsB2 = &Bs[wid*32 + 16][0];

    f32x4 acc[4][4];
    for (int i = 0; i < 4; i++) for (int j = 0; j < 4; j++)
        acc[i][j] = (f32x4){0.f, 0.f, 0.f, 0.f};

    for (int kt = 0; kt < DM; kt += 32) {
        gload_lds16(AgL + kt, ldsA1);
        gload_lds16(AgH + kt, ldsA2);
        gload_lds16(BgL + kt, ldsB1);
        gload_lds16(BgH + kt, ldsB2);
        __syncthreads();
        short8 af[4], bf[4];
        for (int i = 0; i < 4; i++) af[i] = *(const short8*)&As[wm + i*16 + l16][q4*8];
        for (int i = 0; i < 4; i++) bf[i] = *(const short8*)&Bs[wn + i*16 + l16][q4*8];
        for (int mi = 0; mi < 4; mi++)
            for (int ni = 0; ni < 4; ni++)
                acc[mi][ni] = __builtin_amdgcn_mfma_f32_16x16x32_bf16(af[mi], bf[ni], acc[mi][ni], 0, 0, 0);
        __syncthreads();
    }

    const int sel = n0 / DM;
    const float* bias = (sel == 0) ? bq : (sel == 1) ? bk : bv;
    for (int ni = 0; ni < 4; ni++) {
        const int col = n0 + wn + ni*16 + l16;
        const int c = col - sel * DM;
        const float bsv = bias[c];
        const int h = c >> 6, d = c & 63;
        for (int mi = 0; mi < 4; mi++) {
            for (int r = 0; r < 4; r++) {
                const int row = m0 + wm + mi*16 + q4*4 + r;
                const int b = row >> 11, s = row & 2047;
                const int bh = b * NH + h;
                float v = acc[mi][ni][r] + bsv;
                if (sel == 0) {
                    Qb[(bh*SS + s)*DKH + d] = f2bf(v * 0.125f);   // fold 1/sqrt(dk), exact
                } else if (sel == 1) {
                    Kb[(bh*SS + s)*DKH + d] = f2bf(v);
                } else {
                    Vt[(bh*DKH + d)*SS + s] = f2bf(v);            // V pre-transposed
                }
            }
        }
    }
}

// ---- causal flash attention with split-K load balance ----
// qblk 0..15: one block (1..16 tiles, writes ctx directly).
// qblk 16..31: TWO blocks over disjoint key ranges (8..16 tiles each); each writes
// raw fp32 O-partials + l-partials to disjoint scratch (pure-sum merge, no atomics).
// Grid 1152 = 24 bh x 48; bh = lin%24 pins XCD; heavy-ish first via j mapping.
__launch_bounds__(256)
__global__ void k_attn(const unsigned short* __restrict__ Qb,
                       const unsigned short* __restrict__ Kb,
                       const unsigned short* __restrict__ Vt,
                       unsigned short* __restrict__ ctx,
                       float* __restrict__ Op, float* __restrict__ Lp) {
    __shared__ __align__(16) unsigned short Ks[2][64][72];
    __shared__ __align__(16) unsigned short Vs[2][64][72];
    __shared__ __align__(16) unsigned short P[4][16][68];
    const int t = threadIdx.x;
    const int wid = t >> 6, lane = t & 63, q4 = lane >> 4, l16 = lane & 15;
    const int lin = blockIdx.x;               // 0..1151
    const int bh = lin % (BB * NH);
    const int j = lin / (BB * NH);            // 0..47
    int qblk, k0, k1, half;
    bool split;
    if (j < 32) {                             // splits first (heaviest)
        split = true;
        qblk = 31 - (j >> 1);
        half = j & 1;
        const int n = qblk + 1, nh = n >> 1;
        k0 = half ? nh : 0;
        k1 = half ? n : nh;
    } else {
        split = false; half = 0;
        qblk = 47 - j;                        // 15..0
        k0 = 0; k1 = qblk + 1;
    }
    const int b = bh / NH, h = bh - b * NH;
    const int qw = qblk * 64 + wid * 16;      // this wave's 16 q-rows

    const unsigned short* Qp = Qb + (size_t)bh * SS * DKH;
    const unsigned short* Kp = Kb + (size_t)bh * SS * DKH;
    const unsigned short* Vp = Vt + (size_t)bh * DKH * SS;

    const int sr = t >> 3;                    // 0..31
    const int sc = (t & 7) * 8;               // short offset 0..56

    short8 qf[2];
    for (int kc = 0; kc < 2; kc++)
        qf[kc] = *(const short8*)(Qp + (qw + l16)*DKH + kc*32 + q4*8);

    f32x4 accO[4];
    for (int jj = 0; jj < 4; jj++) accO[jj] = (f32x4){0.f, 0.f, 0.f, 0.f};
    float lacc[4] = {0.f, 0.f, 0.f, 0.f};

    // prologue: stage tile k0 into buffer 0
    {
        const int kb0 = k0 * 64;
        uint4 ka = *(const uint4*)(Kp + (size_t)(kb0 + sr)      * DKH + sc);
        uint4 kb = *(const uint4*)(Kp + (size_t)(kb0 + sr + 32) * DKH + sc);
        uint4 va = *(const uint4*)(Vp + (size_t)(sr)      * SS + kb0 + sc);
        uint4 vb = *(const uint4*)(Vp + (size_t)(sr + 32) * SS + kb0 + sc);
        *(uint4*)&Ks[0][sr][sc]      = ka;
        *(uint4*)&Ks[0][sr + 32][sc] = kb;
        *(uint4*)&Vs[0][sr][sc]      = va;
        *(uint4*)&Vs[0][sr + 32][sc] = vb;
    }
    __syncthreads();

    for (int kt = k0; kt < k1; kt++) {
        const int cb = (kt - k0) & 1, nb = cb ^ 1;
        const bool hasN = (kt + 1 < k1);
        uint4 nk0, nk1, nv0, nv1;
        if (hasN) {
            const int kn = (kt + 1) * 64;
            nk0 = *(const uint4*)(Kp + (size_t)(kn + sr)      * DKH + sc);
            nk1 = *(const uint4*)(Kp + (size_t)(kn + sr + 32) * DKH + sc);
            nv0 = *(const uint4*)(Vp + (size_t)(sr)      * SS + kn + sc);
            nv1 = *(const uint4*)(Vp + (size_t)(sr + 32) * SS + kn + sc);
        }
        short8 kf[4][2];
        #pragma unroll
        for (int ni = 0; ni < 4; ni++)
            #pragma unroll
            for (int kc = 0; kc < 2; kc++)
                kf[ni][kc] = *(const short8*)&Ks[cb][ni*16 + l16][kc*32 + q4*8];
        f32x4 S[4];
        #pragma unroll
        for (int jj = 0; jj < 4; jj++) S[jj] = (f32x4){0.f, 0.f, 0.f, 0.f};
        #pragma unroll
        for (int ni = 0; ni < 4; ni++) {
            S[ni] = __builtin_amdgcn_mfma_f32_16x16x32_bf16(qf[0], kf[ni][0], S[ni], 0, 0, 0);
            S[ni] = __builtin_amdgcn_mfma_f32_16x16x32_bf16(qf[1], kf[ni][1], S[ni], 0, 0, 0);
        }
        if (kt == qblk) {                     // diagonal tile (only last full/half1 block)
            #pragma unroll
            for (int ni = 0; ni < 4; ni++) {
                const int pr = q4*4, pc = ni*16 + l16;
                if (ni > wid) {
                    P[wid][pr+0][pc] = 0; P[wid][pr+1][pc] = 0;
                    P[wid][pr+2][pc] = 0; P[wid][pr+3][pc] = 0;
                    continue;
                }
                float p[4];
                if (ni == wid) {
                    #pragma unroll
                    for (int r = 0; r < 4; r++) {
                        const int qrow = qw + q4*4 + r;
                        const int key = qblk*64 + ni*16 + l16;
                        p[r] = (key > qrow) ? 0.f : __expf(S[ni][r]);
                        lacc[r] += p[r];
                    }
                } else {
                    #pragma unroll
                    for (int r = 0; r < 4; r++) { p[r] = __expf(S[ni][r]); lacc[r] += p[r]; }
                }
                union { __hip_bfloat162 v; unsigned u; } u01, u23;
                u01.v = __float22bfloat162_rn(make_float2(p[0], p[1]));
                u23.v = __float22bfloat162_rn(make_float2(p[2], p[3]));
                P[wid][pr+0][pc] = (unsigned short)(u01.u & 0xffffu);
                P[wid][pr+1][pc] = (unsigned short)(u01.u >> 16);
                P[wid][pr+2][pc] = (unsigned short)(u23.u & 0xffffu);
                P[wid][pr+3][pc] = (unsigned short)(u23.u >> 16);
            }
        } else {
            #pragma unroll
            for (int ni = 0; ni < 4; ni++) {
                float p[4];
                #pragma unroll
                for (int r = 0; r < 4; r++) { p[r] = __expf(S[ni][r]); lacc[r] += p[r]; }
                union { __hip_bfloat162 v; unsigned u; } u01, u23;
                u01.v = __float22bfloat162_rn(make_float2(p[0], p[1]));
                u23.v = __float22bfloat162_rn(make_float2(p[2], p[3]));
                const int pr = q4*4, pc = ni*16 + l16;
                P[wid][pr+0][pc] = (unsigned short)(u01.u & 0xffffu);
                P[wid][pr+1][pc] = (unsigned short)(u01.u >> 16);
                P[wid][pr+2][pc] = (unsigned short)(u23.u & 0xffffu);
                P[wid][pr+3][pc] = (unsigned short)(u23.u >> 16);
            }
        }
        asm volatile("s_waitcnt lgkmcnt(0)" ::: "memory");
        short8 pf[2];
        #pragma unroll
        for (int kc = 0; kc < 2; kc++)
            pf[kc] = *(const short8*)&P[wid][l16][kc*32 + q4*8];
        short8 vf[4][2];
        #pragma unroll
        for (int ndi = 0; ndi < 4; ndi++)
            #pragma unroll
            for (int kc = 0; kc < 2; kc++)
                vf[ndi][kc] = *(const short8*)&Vs[cb][ndi*16 + l16][kc*32 + q4*8];
        #pragma unroll
        for (int ndi = 0; ndi < 4; ndi++)
            #pragma unroll
            for (int kc = 0; kc < 2; kc++)
                accO[ndi] = __builtin_amdgcn_mfma_f32_16x16x32_bf16(pf[kc], vf[ndi][kc], accO[ndi], 0, 0, 0);
        if (hasN) {
            *(uint4*)&Ks[nb][sr][sc]      = nk0;
            *(uint4*)&Ks[nb][sr + 32][sc] = nk1;
            *(uint4*)&Vs[nb][sr][sc]      = nv0;
            *(uint4*)&Vs[nb][sr + 32][sc] = nv1;
        }
        __syncthreads();
    }

    if (!split) {
        // full block: reduce l, normalize, write bf16 ctx
        for (int r = 0; r < 4; r++) {
            float l = lacc[r];
            for (int off = 1; off < 16; off <<= 1) l += __shfl_xor(l, off);
            const float inv = 1.0f / l;
            const int s = qw + q4*4 + r;
            for (int ni = 0; ni < 4; ni++)
                ctx[((size_t)(b*SS + s))*DM + h*64 + ni*16 + l16] = f2bf(accO[ni][r] * inv);
        }
    } else {
        // split block: raw partials to disjoint scratch slot
        const size_t e = ((size_t)(bh*16 + (qblk - 16)) * 2 + half);
        float* Od = Op + e * 64 * 64;
        for (int r = 0; r < 4; r++) {
            float l = lacc[r];
            for (int off = 1; off < 16; off <<= 1) l += __shfl_xor(l, off);
            const int row = wid*16 + q4*4 + r;
            if (l16 == 0) Lp[e*64 + row] = l;
            for (int ni = 0; ni < 4; ni++)
                Od[row*64 + ni*16 + l16] = accO[ni][r];
        }
    }
}

// ---- merge split-K partials: ctx = (Oa+Ob)/(la+lb) for qblk 16..31 ----
__launch_bounds__(256)
__global__ void k_merge(const float* __restrict__ Op, const float* __restrict__ Lp,
                        unsigned short* __restrict__ ctx) {
    const int idx = blockIdx.x * 256 + threadIdx.x;   // 24*16*64*64 = 1,572,864
    const int col = idx & 63;
    const int row = (idx >> 6) & 63;
    const int qb  = (idx >> 12) & 15;
    const int bh  = idx >> 16;
    const size_t e0 = ((size_t)(bh*16 + qb) * 2) * 4096;
    const float O = Op[e0 + row*64 + col] + Op[e0 + 4096 + row*64 + col];
    const size_t le = ((size_t)(bh*16 + qb) * 2) * 64;
    const float l = Lp[le + row] + Lp[le + 64 + row];
    const int b = bh / NH, h = bh - b * NH;
    const int s = (qb + 16) * 64 + row;
    ctx[((size_t)(b*SS + s))*DM + h*64 + col] = f2bf(O / l);
}

// ---- output projection: 128x64 tiles, BK=32 (R9 form) ----
__launch_bounds__(256)
__global__ void k_gemm_proj(const unsigned short* __restrict__ ctx,
                            const unsigned short* __restrict__ woT,
                            const float* __restrict__ bo,
                            float* __restrict__ out) {
    __shared__ __align__(16) unsigned short As[128][32];
    __shared__ __align__(16) unsigned short Bs[64][32];
    const int t = threadIdx.x;
    const int m0 = blockIdx.x * 128;
    const int n0 = blockIdx.y * 64;
    const int wid = t >> 6, lane = t & 63, q4 = lane >> 4, l16 = lane & 15;
    const int wm = (wid >> 1) * 64, wn = (wid & 1) * 32;

    const int srowA = wid * 32 + (lane >> 2);
    const int srowB = wid * 16 + (lane >> 2);
    const int koff = (lane & 3) * 8;
    const unsigned short* AgL = ctx + (size_t)(m0 + srowA) * DM + koff;
    const unsigned short* AgH = AgL + (size_t)16 * DM;
    const unsigned short* BgL = woT + (size_t)(n0 + srowB) * DM + koff;
    unsigned short* ldsA1 = &As[wid*32][0];
    unsigned short* ldsA2 = &As[wid*32 + 16][0];
    unsigned short* ldsB1 = &Bs[wid*16][0];

    f32x4 acc[4][2];
    for (int i = 0; i < 4; i++) for (int j = 0; j < 2; j++)
        acc[i][j] = (f32x4){0.f, 0.f, 0.f, 0.f};

    for (int kt = 0; kt < DM; kt += 32) {
        gload_lds16(AgL + kt, ldsA1);
        gload_lds16(AgH + kt, ldsA2);
        gload_lds16(BgL + kt, ldsB1);
        __syncthreads();
        short8 af[4], bf[2];
        for (int i = 0; i < 4; i++) af[i] = *(const short8*)&As[wm + i*16 + l16][q4*8];
        for (int i = 0; i < 2; i++) bf[i] = *(const short8*)&Bs[wn + i*16 + l16][q4*8];
        for (int mi = 0; mi < 4; mi++)
            for (int ni = 0; ni < 2; ni++)
                acc[mi][ni] = __builtin_amdgcn_mfma_f32_16x16x32_bf16(af[mi], bf[ni], acc[mi][ni], 0, 0, 0);
        __syncthreads();
    }

    for (int ni = 0; ni < 2; ni++) {
        const int col = n0 + wn + ni*16 + l16;
        const float bsv = bo[col];
        for (int mi = 0; mi < 4; mi++) {
            for (int r = 0; r < 4; r++) {
                const int row = m0 + wm + mi*16 + q4*4 + r;
                out[(size_t)row * DM + col] = acc[mi][ni][r] + bsv;
            }
        }
    }
}

extern "C" void kernel_launch(void* const* d_in, const int* in_sizes, int n_in,
                              void* d_out, int out_size, void* d_ws, size_t ws_size,
                              hipStream_t stream) {
    const float* x  = (const float*)d_in[0];
    const float* wq = (const float*)d_in[2];
    const float* bq = (const float*)d_in[3];
    const float* wk = (const float*)d_in[4];
    const float* bk = (const float*)d_in[5];
    const float* wv = (const float*)d_in[6];
    const float* bv = (const float*)d_in[7];
    const float* wo = (const float*)d_in[8];
    const float* bo = (const float*)d_in[9];
    float* out = (float*)d_out;

    unsigned short* xb  = (unsigned short*)d_ws;           // 4096*768
    unsigned short* wT  = xb + (size_t)MT * DM;            // 4*768*768
    unsigned short* Qb  = wT + (size_t)4 * DM * DM;        // 24*2048*64
    unsigned short* Kb  = Qb + (size_t)BB * NH * SS * DKH;
    unsigned short* Vt  = Kb + (size_t)BB * NH * SS * DKH; // [bh][dk][s]
    unsigned short* ctx = Vt + (size_t)BB * NH * SS * DKH; // 4096*768
    float* Op = (float*)(ctx + (size_t)MT * DM);           // 24*16*2*4096 fp32
    float* Lp = Op + (size_t)24 * 16 * 2 * 4096;           // 24*16*2*64 fp32

    k_conv<<<3072 + 2304, 256, 0, stream>>>(x, xb, wq, wk, wv, wo, wT);
    dim3 g1(MT / 128, NQKV / 128);
    k_gemm_qkv<<<g1, 256, 0, stream>>>(xb, wT, bq, bk, bv, Qb, Kb, Vt);
    k_attn<<<dim3(48 * BB * NH), 256, 0, stream>>>(Qb, Kb, Vt, ctx, Op, Lp);
    k_merge<<<(24*16*64*64) / 256, 256, 0, stream>>>(Op, Lp, ctx);
    dim3 g3(MT / 128, DM / 64);
    k_gemm_proj<<<g3, 256, 0, stream>>>(ctx, wT + (size_t)3 * DM * DM, bo, out);
}

// Round 12
// 176.142 us; speedup vs baseline: 1.0388x; 1.0388x over previous
//
#include <hip/hip_runtime.h>
#include <hip/hip_bf16.h>
#include <stdint.h>

#define DM   768
#define NH   12
#define DKH  64
#define BB   2
#define SS   2048
#define MT   (BB*SS)          // 4096 rows total
#define NQKV (3*DM)           // 2304

typedef __attribute__((ext_vector_type(8))) short short8;
typedef __attribute__((ext_vector_type(4))) float f32x4;

__device__ __forceinline__ unsigned short f2bf(float f) {
    union { float f; unsigned u; } v; v.f = f;
    unsigned r = v.u + 0x7fffu + ((v.u >> 16) & 1u);
    return (unsigned short)(r >> 16);
}

// async global->LDS, 16B per lane; dst = wave-uniform base + lane*16
__device__ __forceinline__ void gload_lds16(const unsigned short* g, unsigned short* l) {
    __builtin_amdgcn_global_load_lds((const __attribute__((address_space(1))) void*)g,
                                     (__attribute__((address_space(3))) void*)l, 16, 0, 0);
}

// ---- fused input/weight conversion (one launch) ----
__launch_bounds__(256)
__global__ void k_conv(const float* __restrict__ x, unsigned short* __restrict__ xb,
                       const float* __restrict__ wq, const float* __restrict__ wk,
                       const float* __restrict__ wv, const float* __restrict__ wo,
                       unsigned short* __restrict__ wT) {
    __shared__ float tile[32][33];
    const int t = threadIdx.x;
    if (blockIdx.x < 3072) {
        int i = blockIdx.x * 256 + t;
        const float4 v = ((const float4*)x)[i];
        ushort4 o;
        o.x = f2bf(v.x); o.y = f2bf(v.y); o.z = f2bf(v.z); o.w = f2bf(v.w);
        ((ushort4*)xb)[i] = o;
    } else {
        const int cid = blockIdx.x - 3072;            // 0..2303
        const int sel = cid / 576;
        const int rem = cid - sel * 576;
        const int kb = rem / 24, nb = rem - (rem / 24) * 24;
        const float* w = (sel == 0) ? wq : (sel == 1) ? wk : (sel == 2) ? wv : wo;
        const int k0 = kb * 32, n0 = nb * 32;
        const int tx = t & 31, ty = t >> 5;           // (32, 8)
        #pragma unroll
        for (int j = 0; j < 4; j++)
            tile[ty + 8*j][tx] = w[(size_t)(k0 + ty + 8*j) * DM + n0 + tx];
        __syncthreads();
        #pragma unroll
        for (int j = 0; j < 4; j++)
            wT[(size_t)(sel*DM + n0 + ty + 8*j) * DM + k0 + tx] = f2bf(tile[tx][ty + 8*j]);
    }
}

// ---- fused QKV projection, BK=32: Q,K [bh][s][dk] (Q pre-scaled 0.125), V^T [bh][dk][s]
__launch_bounds__(256)
__global__ void k_gemm_qkv(const unsigned short* __restrict__ xb,
                           const unsigned short* __restrict__ wT,
                           const float* __restrict__ bq, const float* __restrict__ bk,
                           const float* __restrict__ bv,
                           unsigned short* __restrict__ Qb,
                           unsigned short* __restrict__ Kb,
                           unsigned short* __restrict__ Vt) {
    __shared__ __align__(16) unsigned short As[128][32];
    __shared__ __align__(16) unsigned short Bs[128][32];
    const int t = threadIdx.x;
    const int m0 = blockIdx.x * 128;
    const int n0 = blockIdx.y * 128;
    const int wid = t >> 6, lane = t & 63, q4 = lane >> 4, l16 = lane & 15;
    const int wm = (wid >> 1) * 64, wn = (wid & 1) * 64;

    const int srow = wid * 32 + (lane >> 2);
    const int koff = (lane & 3) * 8;
    const unsigned short* AgL = xb + (size_t)(m0 + srow) * DM + koff;
    const unsigned short* AgH = AgL + (size_t)16 * DM;
    const unsigned short* BgL = wT + (size_t)(n0 + srow) * DM + koff;
    const unsigned short* BgH = BgL + (size_t)16 * DM;
    unsigned short* ldsA1 = &As[wid*32][0];
    unsigned short* ldsA2 = &As[wid*32 + 16][0];
    unsigned short* ldsB1 = &Bs[wid*32][0];
    unsigned short* ldsB2 = &Bs[wid*32 + 16][0];

    f32x4 acc[4][4];
    for (int i = 0; i < 4; i++) for (int j = 0; j < 4; j++)
        acc[i][j] = (f32x4){0.f, 0.f, 0.f, 0.f};

    for (int kt = 0; kt < DM; kt += 32) {
        gload_lds16(AgL + kt, ldsA1);
        gload_lds16(AgH + kt, ldsA2);
        gload_lds16(BgL + kt, ldsB1);
        gload_lds16(BgH + kt, ldsB2);
        __syncthreads();
        short8 af[4], bf[4];
        for (int i = 0; i < 4; i++) af[i] = *(const short8*)&As[wm + i*16 + l16][q4*8];
        for (int i = 0; i < 4; i++) bf[i] = *(const short8*)&Bs[wn + i*16 + l16][q4*8];
        for (int mi = 0; mi < 4; mi++)
            for (int ni = 0; ni < 4; ni++)
                acc[mi][ni] = __builtin_amdgcn_mfma_f32_16x16x32_bf16(af[mi], bf[ni], acc[mi][ni], 0, 0, 0);
        __syncthreads();
    }

    const int sel = n0 / DM;
    const float* bias = (sel == 0) ? bq : (sel == 1) ? bk : bv;
    for (int ni = 0; ni < 4; ni++) {
        const int col = n0 + wn + ni*16 + l16;
        const int c = col - sel * DM;
        const float bsv = bias[c];
        const int h = c >> 6, d = c & 63;
        for (int mi = 0; mi < 4; mi++) {
            for (int r = 0; r < 4; r++) {
                const int row = m0 + wm + mi*16 + q4*4 + r;
                const int b = row >> 11, s = row & 2047;
                const int bh = b * NH + h;
                float v = acc[mi][ni][r] + bsv;
                if (sel == 0) {
                    Qb[(bh*SS + s)*DKH + d] = f2bf(v * 0.125f);   // fold 1/sqrt(dk), exact
                } else if (sel == 1) {
                    Kb[(bh*SS + s)*DKH + d] = f2bf(v);
                } else {
                    Vt[(bh*DKH + d)*SS + s] = f2bf(v);            // V pre-transposed
                }
            }
        }
    }
}

// ---- causal flash attention: R8 engine (best 43.4 us) + hoisted vf reads ----
// 768 blocks (3/CU), 4 waves x 16 q-rows, dbuf LDS K/V, heavy-first, XCD pin.
__launch_bounds__(256)
__global__ void k_attn(const unsigned short* __restrict__ Qb,
                       const unsigned short* __restrict__ Kb,
                       const unsigned short* __restrict__ Vt,
                       unsigned short* __restrict__ ctx) {
    __shared__ __align__(16) unsigned short Ks[2][64][72];
    __shared__ __align__(16) unsigned short Vs[2][64][72];
    __shared__ __align__(16) unsigned short P[4][16][68];
    const int t = threadIdx.x;
    const int wid = t >> 6, lane = t & 63, q4 = lane >> 4, l16 = lane & 15;
    const int lin = blockIdx.x;               // 0..767
    const int bh = lin % (BB * NH);
    const int qblk = 31 - lin / (BB * NH);    // heavy-first
    const int b = bh / NH, h = bh - b * NH;
    const int qw = qblk * 64 + wid * 16;      // this wave's 16 q-rows

    const unsigned short* Qp = Qb + (size_t)bh * SS * DKH;
    const unsigned short* Kp = Kb + (size_t)bh * SS * DKH;
    const unsigned short* Vp = Vt + (size_t)bh * DKH * SS;

    const int sr = t >> 3;                    // 0..31
    const int sc = (t & 7) * 8;               // short offset 0..56

    short8 qf[2];
    for (int kc = 0; kc < 2; kc++)
        qf[kc] = *(const short8*)(Qp + (qw + l16)*DKH + kc*32 + q4*8);

    f32x4 accO[4];
    for (int j = 0; j < 4; j++) accO[j] = (f32x4){0.f, 0.f, 0.f, 0.f};
    float lacc[4] = {0.f, 0.f, 0.f, 0.f};

    {
        uint4 k0 = *(const uint4*)(Kp + (size_t)(sr)      * DKH + sc);
        uint4 k1 = *(const uint4*)(Kp + (size_t)(sr + 32) * DKH + sc);
        uint4 v0 = *(const uint4*)(Vp + (size_t)(sr)      * SS  + sc);
        uint4 v1 = *(const uint4*)(Vp + (size_t)(sr + 32) * SS  + sc);
        *(uint4*)&Ks[0][sr][sc]      = k0;
        *(uint4*)&Ks[0][sr + 32][sc] = k1;
        *(uint4*)&Vs[0][sr][sc]      = v0;
        *(uint4*)&Vs[0][sr + 32][sc] = v1;
    }
    __syncthreads();

    for (int kt = 0; kt <= qblk; kt++) {
        const int cb = kt & 1, nb = cb ^ 1;
        const bool hasN = (kt < qblk);
        uint4 nk0, nk1, nv0, nv1;
        if (hasN) {
            const int kn = (kt + 1) * 64;
            nk0 = *(const uint4*)(Kp + (size_t)(kn + sr)      * DKH + sc);
            nk1 = *(const uint4*)(Kp + (size_t)(kn + sr + 32) * DKH + sc);
            nv0 = *(const uint4*)(Vp + (size_t)(sr)      * SS + kn + sc);
            nv1 = *(const uint4*)(Vp + (size_t)(sr + 32) * SS + kn + sc);
        }
        short8 kf[4][2];
        #pragma unroll
        for (int ni = 0; ni < 4; ni++)
            #pragma unroll
            for (int kc = 0; kc < 2; kc++)
                kf[ni][kc] = *(const short8*)&Ks[cb][ni*16 + l16][kc*32 + q4*8];
        f32x4 S[4];
        #pragma unroll
        for (int j = 0; j < 4; j++) S[j] = (f32x4){0.f, 0.f, 0.f, 0.f};
        #pragma unroll
        for (int ni = 0; ni < 4; ni++) {
            S[ni] = __builtin_amdgcn_mfma_f32_16x16x32_bf16(qf[0], kf[ni][0], S[ni], 0, 0, 0);
            S[ni] = __builtin_amdgcn_mfma_f32_16x16x32_bf16(qf[1], kf[ni][1], S[ni], 0, 0, 0);
        }
        // hoist V-fragment reads: their ds_read latency overlaps the exp VALU below
        short8 vf[4][2];
        #pragma unroll
        for (int ndi = 0; ndi < 4; ndi++)
            #pragma unroll
            for (int kc = 0; kc < 2; kc++)
                vf[ndi][kc] = *(const short8*)&Vs[cb][ndi*16 + l16][kc*32 + q4*8];
        if (kt == qblk) {
            #pragma unroll
            for (int ni = 0; ni < 4; ni++) {
                const int pr = q4*4, pc = ni*16 + l16;
                if (ni > wid) {
                    P[wid][pr+0][pc] = 0; P[wid][pr+1][pc] = 0;
                    P[wid][pr+2][pc] = 0; P[wid][pr+3][pc] = 0;
                    continue;
                }
                float p[4];
                if (ni == wid) {
                    #pragma unroll
                    for (int r = 0; r < 4; r++) {
                        const int qrow = qw + q4*4 + r;
                        const int key = qblk*64 + ni*16 + l16;
                        p[r] = (key > qrow) ? 0.f : __expf(S[ni][r]);
                        lacc[r] += p[r];
                    }
                } else {
                    #pragma unroll
                    for (int r = 0; r < 4; r++) { p[r] = __expf(S[ni][r]); lacc[r] += p[r]; }
                }
                union { __hip_bfloat162 v; unsigned u; } u01, u23;
                u01.v = __float22bfloat162_rn(make_float2(p[0], p[1]));
                u23.v = __float22bfloat162_rn(make_float2(p[2], p[3]));
                P[wid][pr+0][pc] = (unsigned short)(u01.u & 0xffffu);
                P[wid][pr+1][pc] = (unsigned short)(u01.u >> 16);
                P[wid][pr+2][pc] = (unsigned short)(u23.u & 0xffffu);
                P[wid][pr+3][pc] = (unsigned short)(u23.u >> 16);
            }
        } else {
            #pragma unroll
            for (int ni = 0; ni < 4; ni++) {
                float p[4];
                #pragma unroll
                for (int r = 0; r < 4; r++) { p[r] = __expf(S[ni][r]); lacc[r] += p[r]; }
                union { __hip_bfloat162 v; unsigned u; } u01, u23;
                u01.v = __float22bfloat162_rn(make_float2(p[0], p[1]));
                u23.v = __float22bfloat162_rn(make_float2(p[2], p[3]));
                const int pr = q4*4, pc = ni*16 + l16;
                P[wid][pr+0][pc] = (unsigned short)(u01.u & 0xffffu);
                P[wid][pr+1][pc] = (unsigned short)(u01.u >> 16);
                P[wid][pr+2][pc] = (unsigned short)(u23.u & 0xffffu);
                P[wid][pr+3][pc] = (unsigned short)(u23.u >> 16);
            }
        }
        asm volatile("s_waitcnt lgkmcnt(0)" ::: "memory");   // wave-private P round-trip
        short8 pf[2];
        #pragma unroll
        for (int kc = 0; kc < 2; kc++)
            pf[kc] = *(const short8*)&P[wid][l16][kc*32 + q4*8];
        #pragma unroll
        for (int ndi = 0; ndi < 4; ndi++)
            #pragma unroll
            for (int kc = 0; kc < 2; kc++)
                accO[ndi] = __builtin_amdgcn_mfma_f32_16x16x32_bf16(pf[kc], vf[ndi][kc], accO[ndi], 0, 0, 0);
        if (hasN) {
            *(uint4*)&Ks[nb][sr][sc]      = nk0;
            *(uint4*)&Ks[nb][sr + 32][sc] = nk1;
            *(uint4*)&Vs[nb][sr][sc]      = nv0;
            *(uint4*)&Vs[nb][sr + 32][sc] = nv1;
        }
        __syncthreads();
    }

    for (int r = 0; r < 4; r++) {
        float l = lacc[r];
        for (int off = 1; off < 16; off <<= 1) l += __shfl_xor(l, off);
        const float inv = 1.0f / l;
        const int s = qw + q4*4 + r;
        for (int ni = 0; ni < 4; ni++)
            ctx[((size_t)(b*SS + s))*DM + h*64 + ni*16 + l16] = f2bf(accO[ni][r] * inv);
    }
}

// ---- output projection: 128x64 tiles, BK=32 ----
__launch_bounds__(256)
__global__ void k_gemm_proj(const unsigned short* __restrict__ ctx,
                            const unsigned short* __restrict__ woT,
                            const float* __restrict__ bo,
                            float* __restrict__ out) {
    __shared__ __align__(16) unsigned short As[128][32];
    __shared__ __align__(16) unsigned short Bs[64][32];
    const int t = threadIdx.x;
    const int m0 = blockIdx.x * 128;
    const int n0 = blockIdx.y * 64;
    const int wid = t >> 6, lane = t & 63, q4 = lane >> 4, l16 = lane & 15;
    const int wm = (wid >> 1) * 64, wn = (wid & 1) * 32;

    const int srowA = wid * 32 + (lane >> 2);
    const int srowB = wid * 16 + (lane >> 2);
    const int koff = (lane & 3) * 8;
    const unsigned short* AgL = ctx + (size_t)(m0 + srowA) * DM + koff;
    const unsigned short* AgH = AgL + (size_t)16 * DM;
    const unsigned short* BgL = woT + (size_t)(n0 + srowB) * DM + koff;
    unsigned short* ldsA1 = &As[wid*32][0];
    unsigned short* ldsA2 = &As[wid*32 + 16][0];
    unsigned short* ldsB1 = &Bs[wid*16][0];

    f32x4 acc[4][2];
    for (int i = 0; i < 4; i++) for (int j = 0; j < 2; j++)
        acc[i][j] = (f32x4){0.f, 0.f, 0.f, 0.f};

    for (int kt = 0; kt < DM; kt += 32) {
        gload_lds16(AgL + kt, ldsA1);
        gload_lds16(AgH + kt, ldsA2);
        gload_lds16(BgL + kt, ldsB1);
        __syncthreads();
        short8 af[4], bf[2];
        for (int i = 0; i < 4; i++) af[i] = *(const short8*)&As[wm + i*16 + l16][q4*8];
        for (int i = 0; i < 2; i++) bf[i] = *(const short8*)&Bs[wn + i*16 + l16][q4*8];
        for (int mi = 0; mi < 4; mi++)
            for (int ni = 0; ni < 2; ni++)
                acc[mi][ni] = __builtin_amdgcn_mfma_f32_16x16x32_bf16(af[mi], bf[ni], acc[mi][ni], 0, 0, 0);
        __syncthreads();
    }

    for (int ni = 0; ni < 2; ni++) {
        const int col = n0 + wn + ni*16 + l16;
        const float bsv = bo[col];
        for (int mi = 0; mi < 4; mi++) {
            for (int r = 0; r < 4; r++) {
                const int row = m0 + wm + mi*16 + q4*4 + r;
                out[(size_t)row * DM + col] = acc[mi][ni][r] + bsv;
            }
        }
    }
}

extern "C" void kernel_launch(void* const* d_in, const int* in_sizes, int n_in,
                              void* d_out, int out_size, void* d_ws, size_t ws_size,
                              hipStream_t stream) {
    const float* x  = (const float*)d_in[0];
    const float* wq = (const float*)d_in[2];
    const float* bq = (const float*)d_in[3];
    const float* wk = (const float*)d_in[4];
    const float* bk = (const float*)d_in[5];
    const float* wv = (const float*)d_in[6];
    const float* bv = (const float*)d_in[7];
    const float* wo = (const float*)d_in[8];
    const float* bo = (const float*)d_in[9];
    float* out = (float*)d_out;

    unsigned short* xb  = (unsigned short*)d_ws;           // 4096*768
    unsigned short* wT  = xb + (size_t)MT * DM;            // 4*768*768
    unsigned short* Qb  = wT + (size_t)4 * DM * DM;        // 24*2048*64
    unsigned short* Kb  = Qb + (size_t)BB * NH * SS * DKH;
    unsigned short* Vt  = Kb + (size_t)BB * NH * SS * DKH; // [bh][dk][s]
    unsigned short* ctx = Vt + (size_t)BB * NH * SS * DKH; // 4096*768

    k_conv<<<3072 + 2304, 256, 0, stream>>>(x, xb, wq, wk, wv, wo, wT);
    dim3 g1(MT / 128, NQKV / 128);
    k_gemm_qkv<<<g1, 256, 0, stream>>>(xb, wT, bq, bk, bv, Qb, Kb, Vt);
    k_attn<<<dim3(32 * BB * NH), 256, 0, stream>>>(Qb, Kb, Vt, ctx);
    dim3 g3(MT / 128, DM / 64);
    k_gemm_proj<<<g3, 256, 0, stream>>>(ctx, wT + (size_t)3 * DM * DM, bo, out);
}